// Round 5
// baseline (422.989 us; speedup 1.0000x reference)
//
#include <hip/hip_runtime.h>

typedef unsigned short u16;
typedef unsigned int u32;
typedef __attribute__((ext_vector_type(8))) short short8;
typedef __attribute__((ext_vector_type(4))) float f32x4;

#define NEG (-1e30f)
#define SCL 0.180336880f   // 0.125 / ln(2)  -> exp2 domain

// ---- workspace byte offsets -------------------------------------------------
#define WS_WPQ   (0u)          // 2 MB  bf16 [N=1024][K=1024]  (B^T)
#define WS_WPK   (2u<<20)
#define WS_WPV   (4u<<20)
#define WS_WBIG  (6u<<20)      // 2 MB  bf16 B^T
#define WS_BC    (8u<<20)               // 4 KB f32
#define WS_MB    ((8u<<20)+(1u<<16))    // 32 KB f32 mask bias [B][2048]
#define WS_MP    ((8u<<20)+(3u<<16))    // 128 B int mask partials
#define WS_QP    (9u<<20)      // 16 MB bf16 q-proj (PRE-SCALED by SCL)
#define WS_KP    (25u<<20)
#define WS_VP    (41u<<20)
#define WS_VT    (57u<<20)     // V^T, pre-swizzled: [bh*64+dv][2048 kv]
#define WS_CTX   (73u<<20)     // attention out bf16

// ---- helpers ----------------------------------------------------------------
__device__ __forceinline__ u16 f2b(float f) {
    union { float f; unsigned u; } x; x.f = f;
    unsigned r = x.u + 0x7fffu + ((x.u >> 16) & 1u);   // RNE
    return (u16)(r >> 16);
}

__device__ __forceinline__ u32 cvt_pk(float a, float b) {   // low16=bf16(a), high16=bf16(b)
    u32 r;
    asm("v_cvt_pk_bf16_f32 %0, %1, %2" : "=v"(r) : "v"(a), "v"(b));
    return r;
}

__device__ __forceinline__ void gload16(const void* g, void* lds) {
    __builtin_amdgcn_global_load_lds(
        (const __attribute__((address_space(1))) void*)g,
        (__attribute__((address_space(3))) void*)lds, 16, 0, 0);
}

// ---- small prep kernels -----------------------------------------------------
// Wq/Wk/Wv [H,D,64] -> B^T bf16 [n=h*64+kk][k=d], LDS-transposed (coalesced)
__global__ __launch_bounds__(256) void pack_qkv(const float* __restrict__ Wq,
                                                const float* __restrict__ Wk,
                                                const float* __restrict__ Wv,
                                                u16* __restrict__ pq,
                                                u16* __restrict__ pk,
                                                u16* __restrict__ pv) {
    __shared__ u16 T[64][68];
    const int dt = blockIdx.x, h = blockIdx.y;
    const int r = threadIdx.x >> 2, c0 = (threadIdx.x & 3) * 16;
    const float* srcs[3] = {Wq, Wk, Wv};
    u16* dsts[3] = {pq, pk, pv};
#pragma unroll
    for (int m = 0; m < 3; ++m) {
        const float* src = srcs[m] + (size_t)(h * 1024 + dt * 64 + r) * 64 + c0;
#pragma unroll
        for (int i4 = 0; i4 < 4; ++i4) {
            float4 x = *(const float4*)(src + i4 * 4);
            T[c0 + i4*4 + 0][r] = f2b(x.x);
            T[c0 + i4*4 + 1][r] = f2b(x.y);
            T[c0 + i4*4 + 2][r] = f2b(x.z);
            T[c0 + i4*4 + 3][r] = f2b(x.w);
        }
        __syncthreads();
        u16* dst = dsts[m] + (size_t)(h * 64 + r) * 1024 + dt * 64 + c0;
        short8 o0, o1;
#pragma unroll
        for (int i = 0; i < 8; ++i) { o0[i] = (short)T[r][c0 + i]; o1[i] = (short)T[r][c0 + 8 + i]; }
        *(short8*)dst = o0;
        *(short8*)(dst + 8) = o1;
        __syncthreads();
    }
}

// WbigT[n][k=h*64+v] = sum_u Wo[h][v][u] * Wf[h*64+u][n]; grid (4 col-tiles, 16 h)
__global__ __launch_bounds__(256) void make_wbig(const float* __restrict__ Wo,
                                                 const float* __restrict__ Wf,
                                                 u16* __restrict__ wbig) {
    __shared__ float WoL[64][64];
    const int ct = blockIdx.x, h = blockIdx.y;
    const int tid = threadIdx.x;
#pragma unroll
    for (int r = 0; r < 16; ++r) {
        int i = r * 256 + tid;
        WoL[i >> 6][i & 63] = Wo[h * 4096 + i];
    }
    __syncthreads();
    const int n = ct * 256 + tid;
    float wf[64];
#pragma unroll
    for (int u = 0; u < 64; ++u)
        wf[u] = Wf[(size_t)(h * 64 + u) * 1024 + n];
    u16* dst = wbig + (size_t)n * 1024 + h * 64;
    for (int vb = 0; vb < 64; vb += 8) {
        short8 o;
#pragma unroll
        for (int t = 0; t < 8; ++t) {
            int v = vb + t;
            float s = 0.f;
#pragma unroll
            for (int u4 = 0; u4 < 16; ++u4) {
                float4 w4 = *(const float4*)&WoL[v][u4 * 4];
                s += w4.x * wf[u4*4] + w4.y * wf[u4*4+1] + w4.z * wf[u4*4+2] + w4.w * wf[u4*4+3];
            }
            o[t] = (short)f2b(s);
        }
        *(short8*)(dst + vb) = o;
    }
}

// bcomb[n] = bf[n] + sum_x bo[x]*Wf[x][n]; also pmask -> mbias f32 + mpart flags
__global__ __launch_bounds__(256) void make_bcomb(const float* __restrict__ bo,
                                                  const float* __restrict__ bf,
                                                  const float* __restrict__ Wf,
                                                  const unsigned char* __restrict__ pmask,
                                                  float* __restrict__ bc,
                                                  float* __restrict__ mbias,
                                                  int* __restrict__ mpart) {
    __shared__ float red[16][17];
    const int tx = threadIdx.x & 15, ty = threadIdx.x >> 4;
    const int n = blockIdx.x * 16 + tx;
    float s = 0.f;
#pragma unroll
    for (int i = 0; i < 64; ++i) {
        int x = ty * 64 + i;
        s += bo[x] * Wf[(size_t)x * 1024 + n];
    }
    red[ty][tx] = s;

    int t = blockIdx.x * 256 + threadIdx.x;
    int v = 0;
    if (t < 8192) {
        v = pmask[t] ? 1 : 0;
        mbias[t] = v ? NEG : 0.f;
    }
    int ba = __syncthreads_or(v);
    if (threadIdx.x == 0 && blockIdx.x < 32) mpart[blockIdx.x] = ba;

    if (ty == 0) {
        float tt = bf[n];
#pragma unroll
        for (int y = 0; y < 16; ++y) tt += red[y][tx];
        bc[n] = tt;
    }
}

// v bf16 [B,2048,1024] -> Vt bf16 [bh*64+dv][2048], kv-chunks XOR-swizzled by dv
__global__ __launch_bounds__(256) void vtrans(const u16* __restrict__ vp,
                                              u16* __restrict__ vt) {
    const int kvt = blockIdx.x, bh = blockIdx.y, b = bh >> 4, h = bh & 15;
    const int tid = threadIdx.x;
    __shared__ u16 T[64][72];
    {
        int kv_r = tid >> 2, dg = (tid & 3) * 16;
        const u16* src = vp + ((size_t)(b * 2048 + kvt * 64 + kv_r)) * 1024 + h * 64 + dg;
        short8 x0 = *(const short8*)src;
        short8 x1 = *(const short8*)(src + 8);
#pragma unroll
        for (int i = 0; i < 8; ++i) { T[dg + i][kv_r] = (u16)x0[i]; T[dg + 8 + i][kv_r] = (u16)x1[i]; }
    }
    __syncthreads();
    {
        int dv = tid >> 2, cg = (tid & 3) * 16;
        int swz = (dv & 7) << 3;
        u16* dst = vt + ((size_t)(bh * 64 + dv)) * 2048 + kvt * 64;
#pragma unroll
        for (int q = 0; q < 2; ++q) {
            int c0 = cg + q * 8;
            short8 y;
#pragma unroll
            for (int i = 0; i < 8; ++i) y[i] = (short)T[dv][c0 + i];
            *(short8*)(dst + (c0 ^ swz)) = y;
        }
    }
}

// ---- bf16 MFMA GEMM, BM=128 BN=256 BK=64, 8 waves, dbuf ---------------------
// C[M,N] = (A @ Bt^T + bias) * oscale.  A_F32: A is f32, reg-staged + cvt.
// Wave grid 2M x 4N; per-wave tile 64x64 (4x4 16x16 fragments).
template <int A_F32, int OUT_BF16>
__global__ __launch_bounds__(512) void gemm_bn256(const void* __restrict__ Av,
                                                  const u16* __restrict__ Bt,
                                                  const float* __restrict__ bias,
                                                  void* __restrict__ Cv,
                                                  int M, int N, int K, float oscale) {
    __shared__ __align__(16) u16 As[2][128 * 64];
    __shared__ __align__(16) u16 Bs[2][256 * 64];
    const int tid = threadIdx.x;
    const int lane = tid & 63, w = tid >> 6;        // 8 waves
    const int li = lane & 15, g = lane >> 4;
    const int bm = blockIdx.y * 128, bn = blockIdx.x * 256;
    const int wm = w >> 2, wn = w & 3;

    // --- per-thread staging pointers (hoisted) ---
    const u16* bsrc[4];
    int bdst[4];
#pragma unroll
    for (int r = 0; r < 4; ++r) {
        int ch = (r * 8 + w) * 64 + lane;           // 0..2047
        int row = ch >> 3;
        int ck = (ch & 7) ^ (row & 7);
        bsrc[r] = Bt + (size_t)(bn + row) * K + ck * 8;
        bdst[r] = (r * 8 + w) * 1024;               // wave-uniform byte base
    }
    const float* afsrc[2];
    const u16*   a16src[2];
    int aoff[2], adst[2];
#pragma unroll
    for (int r = 0; r < 2; ++r) {
        int ch = (r * 8 + w) * 64 + lane;           // 0..1023
        int row = ch >> 3;
        int ck = (ch & 7) ^ (row & 7);
        if (A_F32) afsrc[r] = (const float*)Av + (size_t)(bm + row) * K + ck * 8;
        else       a16src[r] = (const u16*)Av + (size_t)(bm + row) * K + ck * 8;
        aoff[r] = ch * 8;                           // u16 element offset (linear dst)
        adst[r] = (r * 8 + w) * 1024;
    }

    auto STAGE_B = [&](int buf) {
#pragma unroll
        for (int r = 0; r < 4; ++r) {
            gload16(bsrc[r], (char*)(Bs[buf]) + bdst[r]);
            bsrc[r] += 64;
        }
    };
    auto STAGE_A16 = [&](int buf) {
#pragma unroll
        for (int r = 0; r < 2; ++r) {
            gload16(a16src[r], (char*)(As[buf]) + adst[r]);
            a16src[r] += 64;
        }
    };
    auto LOAD_A = [&](float4 fa[2][2]) {
#pragma unroll
        for (int r = 0; r < 2; ++r) {
            fa[r][0] = *(const float4*)afsrc[r];
            fa[r][1] = *(const float4*)(afsrc[r] + 4);
            afsrc[r] += 64;
        }
    };
    auto WRITE_A = [&](int buf, float4 fa[2][2]) {
#pragma unroll
        for (int r = 0; r < 2; ++r) {
            u32 q0 = cvt_pk(fa[r][0].x, fa[r][0].y);
            u32 q1 = cvt_pk(fa[r][0].z, fa[r][0].w);
            u32 q2 = cvt_pk(fa[r][1].x, fa[r][1].y);
            u32 q3 = cvt_pk(fa[r][1].z, fa[r][1].w);
            *(uint4*)(As[buf] + aoff[r]) = make_uint4(q0, q1, q2, q3);
        }
    };

    f32x4 acc[4][4];
#pragma unroll
    for (int m = 0; m < 4; ++m)
#pragma unroll
        for (int n = 0; n < 4; ++n) acc[m][n] = (f32x4){0.f, 0.f, 0.f, 0.f};

    // prologue: fill buf 0
    {
        float4 fa[2][2];
        if (A_F32) LOAD_A(fa); else STAGE_A16(0);
        STAGE_B(0);
        if (A_F32) WRITE_A(0, fa);
    }
    __syncthreads();
    int cur = 0;

    for (int k0 = 0; k0 < K; k0 += 64) {
        const bool more = (k0 + 64 < K);
        float4 fa[2][2];
        if (more) {
            if (A_F32) LOAD_A(fa); else STAGE_A16(cur ^ 1);
            STAGE_B(cur ^ 1);
        }
        __builtin_amdgcn_s_setprio(1);
#pragma unroll
        for (int kk = 0; kk < 2; ++kk) {
            short8 a[4], b[4];
#pragma unroll
            for (int m = 0; m < 4; ++m) {
                int row = wm * 64 + m * 16 + li;
                int c = (kk * 4 + g) ^ (row & 7);
                a[m] = *(const short8*)(As[cur] + row * 64 + c * 8);
            }
#pragma unroll
            for (int n = 0; n < 4; ++n) {
                int row = wn * 64 + n * 16 + li;
                int c = (kk * 4 + g) ^ (row & 7);
                b[n] = *(const short8*)(Bs[cur] + row * 64 + c * 8);
            }
#pragma unroll
            for (int m = 0; m < 4; ++m)
#pragma unroll
                for (int n = 0; n < 4; ++n)
                    acc[m][n] = __builtin_amdgcn_mfma_f32_16x16x32_bf16(a[m], b[n], acc[m][n], 0, 0, 0);
        }
        __builtin_amdgcn_s_setprio(0);
        if (more && A_F32) WRITE_A(cur ^ 1, fa);
        __syncthreads();
        cur ^= 1;
    }

#pragma unroll
    for (int n = 0; n < 4; ++n) {
        int col = bn + wn * 64 + n * 16 + li;
        float bv = bias[col];
#pragma unroll
        for (int m = 0; m < 4; ++m)
#pragma unroll
            for (int j = 0; j < 4; ++j) {
                int row = bm + wm * 64 + m * 16 + g * 4 + j;
                float v = (acc[m][n][j] + bv) * oscale;
                if (OUT_BF16) ((u16*)Cv)[(size_t)row * N + col] = f2b(v);
                else          ((float*)Cv)[(size_t)row * N + col] = v;
            }
    }
}

// ---- bf16 MFMA causal flash attention, swapped-QK softmax -------------------
__global__ __launch_bounds__(256) void flash_attn(const u16* __restrict__ qp,
                                                  const u16* __restrict__ kp,
                                                  const u16* __restrict__ vt,
                                                  const float* __restrict__ mbias,
                                                  const int* __restrict__ mpart,
                                                  u16* __restrict__ ctx) {
    const int bh = blockIdx.x, b = bh >> 4, h = bh & 15;
    const int qt = 31 - blockIdx.y;                    // longest blocks dispatch first
    const int tid = threadIdx.x, lane = tid & 63, w = tid >> 6;
    const int li = lane & 15, g = lane >> 4;

    __shared__ __align__(16) u16 Ks[2][64 * 64];
    __shared__ __align__(16) u16 Vs[2][64 * 64];
    __shared__ __align__(16) u16 Ps[64 * 64];

    // hoisted staging pointers
    const u16 *ksrc[2], *vsrc[2];
    int sdst[2];
#pragma unroll
    for (int r = 0; r < 2; ++r) {
        int ch = (r * 4 + w) * 64 + lane;              // 0..511
        int row = ch >> 3, cc = ch & 7;
        int ck = cc ^ (row & 7);
        ksrc[r] = kp + (size_t)(b * 2048 + row) * 1024 + h * 64 + ck * 8;
        vsrc[r] = vt + (size_t)(bh * 64 + row) * 2048 + cc * 8;   // pre-swizzled
        sdst[r] = (r * 4 + w) * 1024;
    }
    auto STAGE = [&](int buf) {
#pragma unroll
        for (int r = 0; r < 2; ++r) {
            gload16(ksrc[r], (char*)(Ks[buf]) + sdst[r]);
            gload16(vsrc[r], (char*)(Vs[buf]) + sdst[r]);
            ksrc[r] += 64 * 1024;
            vsrc[r] += 64;
        }
    };

    // skip to this block's q-tile
#pragma unroll
    for (int r = 0; r < 2; ++r) { /* q rows: qt*64 offset applies to K only via kt; nothing here */ }

    STAGE(0);
    // Q fragments straight to registers (pre-scaled by SCL at projection)
    const int rq = w * 16 + li;
    const u16* qg = qp + (size_t)(b * 2048 + qt * 64 + rq) * 1024 + h * 64;
    short8 aq0 = *(const short8*)(qg + g * 8);
    short8 aq1 = *(const short8*)(qg + 32 + g * 8);

    bool padded;
    {
        int a = 0;
#pragma unroll
        for (int i = 0; i < 8; ++i) a |= mpart[b * 8 + i];
        padded = (a != 0);
    }

    float m_i = NEG, l_i = 0.f;
    f32x4 o_acc[4];
#pragma unroll
    for (int n = 0; n < 4; ++n) o_acc[n] = (f32x4){0.f, 0.f, 0.f, 0.f};

    const float* mb = mbias + (size_t)b * 2048;
    const int swz  = li & 7;                 // K/V LDS chunk swizzle
    const int pswz = (li & 7) ^ (li >> 3);   // P swizzle: breaks li/li+8 bank alias

    __syncthreads();
    int cur = 0;

    auto TILE = [&](int kt, int buf, bool diag) {
        float mcv[16];
        if (padded) {
#pragma unroll
            for (int n = 0; n < 4; ++n)
                *(float4*)(mcv + n * 4) = *(const float4*)(mb + kt * 64 + n * 16 + g * 4);
        }

        f32x4 s[4];
#pragma unroll
        for (int n = 0; n < 4; ++n) s[n] = (f32x4){0.f, 0.f, 0.f, 0.f};
        __builtin_amdgcn_s_setprio(1);
#pragma unroll
        for (int kk = 0; kk < 2; ++kk) {
            short8 aq = kk ? aq1 : aq0;
#pragma unroll
            for (int n = 0; n < 4; ++n) {
                short8 bk = *(const short8*)(Ks[buf] + (n * 16 + li) * 64 + ((kk * 4 + g) ^ swz) * 8);
                s[n] = __builtin_amdgcn_mfma_f32_16x16x32_bf16(bk, aq, s[n], 0, 0, 0);
            }
        }
        __builtin_amdgcn_s_setprio(0);

        float rmax = NEG;
#pragma unroll
        for (int n = 0; n < 4; ++n)
#pragma unroll
            for (int j = 0; j < 4; ++j) {
                float v = s[n][j];
                if (padded) v += mcv[n * 4 + j];
                if (diag && (n * 16 + g * 4 + j) > rq) v = NEG;
                s[n][j] = v;
                rmax = fmaxf(rmax, v);
            }
        rmax = fmaxf(rmax, __shfl_xor(rmax, 16));
        rmax = fmaxf(rmax, __shfl_xor(rmax, 32));

        if (__any(rmax > m_i)) {
            float mn = fmaxf(m_i, rmax);
            float a  = exp2f(m_i - mn);
            m_i = mn;
            l_i *= a;
            float af[4];
#pragma unroll
            for (int j = 0; j < 4; ++j) af[j] = __shfl(a, g * 4 + j);
#pragma unroll
            for (int n = 0; n < 4; ++n)
#pragma unroll
                for (int j = 0; j < 4; ++j) o_acc[n][j] *= af[j];
        }

        float rs = 0.f;
#pragma unroll
        for (int n = 0; n < 4; ++n) {
            float p0 = exp2f(s[n][0] - m_i);
            float p1 = exp2f(s[n][1] - m_i);
            float p2 = exp2f(s[n][2] - m_i);
            float p3 = exp2f(s[n][3] - m_i);
            rs += (p0 + p1) + (p2 + p3);
            u32 lo = cvt_pk(p0, p1), hi = cvt_pk(p2, p3);
            int col = (n * 16 + g * 4) ^ (pswz << 3);
            *(uint2*)(Ps + rq * 64 + col) = make_uint2(lo, hi);
        }
        rs += __shfl_xor(rs, 16);
        rs += __shfl_xor(rs, 32);
        l_i += rs;

        __builtin_amdgcn_s_setprio(1);
#pragma unroll
        for (int kk = 0; kk < 2; ++kk) {
            short8 pa = *(const short8*)(Ps + rq * 64 + ((kk * 4 + g) ^ pswz) * 8);
#pragma unroll
            for (int n = 0; n < 4; ++n) {
                short8 vb = *(const short8*)(Vs[buf] + (n * 16 + li) * 64 + ((kk * 4 + g) ^ swz) * 8);
                o_acc[n] = __builtin_amdgcn_mfma_f32_16x16x32_bf16(pa, vb, o_acc[n], 0, 0, 0);
            }
        }
        __builtin_amdgcn_s_setprio(0);
    };

    for (int kt = 0; kt < qt; ++kt) {
        STAGE(cur ^ 1);
        TILE(kt, cur, false);
        __syncthreads();
        cur ^= 1;
    }
    TILE(qt, cur, true);

    float linv = 1.f / l_i;
    float lr[4];
#pragma unroll
    for (int j = 0; j < 4; ++j) lr[j] = __shfl(linv, g * 4 + j);
#pragma unroll
    for (int n = 0; n < 4; ++n)
#pragma unroll
        for (int j = 0; j < 4; ++j) {
            int rowq = qt * 64 + w * 16 + g * 4 + j;
            ctx[(size_t)(b * 2048 + rowq) * 1024 + h * 64 + n * 16 + li] = f2b(o_acc[n][j] * lr[j]);
        }
}

// ---------------------------------------------------------------------------
extern "C" void kernel_launch(void* const* d_in, const int* in_sizes, int n_in,
                              void* d_out, int out_size, void* d_ws, size_t ws_size,
                              hipStream_t stream) {
    const float* Q  = (const float*)d_in[0];
    const float* K  = (const float*)d_in[1];
    const float* V  = (const float*)d_in[2];
    const unsigned char* pmask = (const unsigned char*)d_in[3];
    const float* Wq = (const float*)d_in[4];
    const float* bq = (const float*)d_in[5];
    const float* Wk = (const float*)d_in[6];
    const float* bk = (const float*)d_in[7];
    const float* Wv = (const float*)d_in[8];
    const float* bv = (const float*)d_in[9];
    const float* Wo = (const float*)d_in[10];
    const float* bo = (const float*)d_in[11];
    const float* Wf = (const float*)d_in[12];
    const float* bf = (const float*)d_in[13];
    float* out = (float*)d_out;
    char*  ws  = (char*)d_ws;

    u16* WPQ = (u16*)(ws + WS_WPQ);  u16* WPK = (u16*)(ws + WS_WPK);
    u16* WPV = (u16*)(ws + WS_WPV);  u16* WBG = (u16*)(ws + WS_WBIG);
    float* BC = (float*)(ws + WS_BC);
    float* MB = (float*)(ws + WS_MB);
    int*   MP = (int*)(ws + WS_MP);
    u16* QP = (u16*)(ws + WS_QP);  u16* KP = (u16*)(ws + WS_KP);  u16* VP = (u16*)(ws + WS_VP);
    u16* VT = (u16*)(ws + WS_VT);  u16* CTX = (u16*)(ws + WS_CTX);

    pack_qkv<<<dim3(16, 16), 256, 0, stream>>>(Wq, Wk, Wv, WPQ, WPK, WPV);
    make_wbig<<<dim3(4, 16), 256, 0, stream>>>(Wo, Wf, WBG);
    make_bcomb<<<64, 256, 0, stream>>>(bo, bf, Wf, pmask, BC, MB, MP);

    dim3 gp(4, 64);   // N/256, M/128
    gemm_bn256<1, 1><<<gp, 512, 0, stream>>>(Q, WPQ, bq, QP, 8192, 1024, 1024, SCL);
    gemm_bn256<1, 1><<<gp, 512, 0, stream>>>(K, WPK, bk, KP, 8192, 1024, 1024, 1.0f);
    gemm_bn256<1, 1><<<gp, 512, 0, stream>>>(V, WPV, bv, VP, 8192, 1024, 1024, 1.0f);

    vtrans<<<dim3(32, 64), 256, 0, stream>>>(VP, VT);

    flash_attn<<<dim3(64, 32), 256, 0, stream>>>(QP, KP, VT, MB, MP, CTX);

    gemm_bn256<0, 0><<<gp, 512, 0, stream>>>(CTX, WBG, BC, out, 8192, 1024, 1024, 1.0f);
}